// Round 15
// baseline (374.921 us; speedup 1.0000x reference)
//
#include <hip/hip_runtime.h>
#include <cmath>

// DHGLayer on MI355X. N=10000, D=128.
// kpre (normalize -> bf16 xnh; fp16 feats/W) -> ksimvc (MEGA: bf16 MFMA sim
// with in-register top-16 scan, interleaved with the 4 knn-independent
// vertex-conv branches) -> kmerge -> krerank (f64 exact top-16) -> kvc3 (knn
// vertex conv) -> kfinal.
// R14 lesson: sim+vc time-share the VALU pipe (sum not max; m114 overlap is
// MFMA-vs-VALU, not VALU-vs-VALU). The real lever: Occupancy 34.7% (32KB LDS
// -> 4 blk/CU) with VGPR only 60. Sim B-tile shrunk to 64 cols (16KB, same
// total staging bytes, 10 tiles x 2 batches) + launch_bounds(256,6) -> 6
// blk/CU = 24 waves, 2.2x TLP against the scan's dependency stalls.

#define N_NODES 10000
#define D 128
#define DQ 32
#define NCB 3
#define T_HE 5
#define HID_SZ 32
#define NCH 16
#define CHUNK 625      // 16 * 625 = 10000
#define TOPK 16
#define TOPM 32

typedef __attribute__((ext_vector_type(8))) short short8;
typedef __attribute__((ext_vector_type(8))) _Float16 half8;
typedef __attribute__((ext_vector_type(4))) float f32x4;
typedef __attribute__((ext_vector_type(16))) float f32x16;

// ---------------- helpers ----------------
__device__ __forceinline__ unsigned bf16rne(float f) {
  unsigned u = __float_as_uint(f);
  return (u + 0x7FFFu + ((u >> 16) & 1u)) >> 16;
}

// ---------------- fused prep: bf16 xnh + fp16 feats + fp16 W + f64 norm ----------------
__global__ __launch_bounds__(256) void kpre(const float* __restrict__ feats,
                                            const float* __restrict__ wc,
                                            const float* __restrict__ wn,
                                            const float* __restrict__ wstr,
                                            unsigned short* __restrict__ xnh,
                                            _Float16* __restrict__ fH16,
                                            double* __restrict__ normD,
                                            _Float16* __restrict__ wH16) {
  int bx = blockIdx.x;
  int tid = threadIdx.x;
  if (bx < 2500) {
    int n = bx * 4 + (tid >> 6);
    int lane = tid & 63;
    float2 v = ((const float2*)(feats + (size_t)n * D))[lane];
    _Float16 p2[2] = {(_Float16)v.x, (_Float16)v.y};
    ((unsigned*)(fH16 + (size_t)n * D))[lane] = *(const unsigned*)p2;
    double ss = (double)v.x * (double)v.x + (double)v.y * (double)v.y;
#pragma unroll
    for (int o = 32; o > 0; o >>= 1) ss += __shfl_xor(ss, o);
    double nd = fmax(sqrt(ss), 1e-12);
    if (lane == 0) normD[n] = nd;
    float inv = (float)(1.0 / nd);
    ((unsigned*)(xnh + (size_t)n * D))[lane] = bf16rne(v.x * inv) | (bf16rne(v.y * inv) << 16);
  } else {
    int p = (bx - 2500) * 256 + tid;
    if (p >= 98304) return;
    int e = p * 2;
    float2 v;
    if (e < 32768) v = *(const float2*)(wc + e);
    else if (e < 65536) v = *(const float2*)(wn + (e - 32768));
    else v = *(const float2*)(wstr + (e - 65536));
    _Float16 p2[2] = {(_Float16)v.x, (_Float16)v.y};
    ((unsigned*)wH16)[p] = *(const unsigned*)p2;
  }
}

// ---------------- sorting-network helpers ----------------
__device__ __forceinline__ void ceu(unsigned& a, unsigned& b) {
  unsigned lo = min(a, b), hi = max(a, b);
  a = lo; b = hi;
}
__device__ __forceinline__ void ceu64(unsigned long long& a, unsigned long long& b) {
  unsigned long long lo = min(a, b), hi = max(a, b);
  a = lo; b = hi;
}
__device__ __forceinline__ void sort16_asc(unsigned (&v)[16]) {
#pragma unroll
  for (int k = 2; k <= 16; k <<= 1) {
#pragma unroll
    for (int j = k >> 1; j > 0; j >>= 1) {
#pragma unroll
      for (int i = 0; i < 16; i++) {
        int x = i ^ j;
        if (x > i) {
          if ((i & k) == 0) ceu(v[i], v[x]);
          else ceu(v[x], v[i]);
        }
      }
    }
  }
}
__device__ __forceinline__ void merge16_asc(unsigned (&run)[16], const unsigned (&b)[16]) {
  unsigned m[16];
#pragma unroll
  for (int i = 0; i < 16; i++) m[i] = max(run[i], b[15 - i]);
#pragma unroll
  for (int j = 8; j > 0; j >>= 1) {
#pragma unroll
    for (int i = 0; i < 16; i++) {
      if ((i & j) == 0) ceu(m[i], m[i + j]);
    }
  }
#pragma unroll
  for (int i = 0; i < 16; i++) run[i] = m[i];
}

// ---------------- vertex-conv device bodies (shared LDS via pointers) ----------------
// LDS layout in smem: idxL (16x33 int, 2112B) | coefP (4x16x33 f32, 8448B) |
// coefS (16x33 f32, 2112B) = 12672B.
__device__ __forceinline__ void vc16_body(int tid, int n0, int tslot,
    int* idxLm, float* coefPm, float* coefSm,
    const _Float16* __restrict__ fH16, const _Float16* __restrict__ wH16,
    const int* __restrict__ idxTab, int istr, int ioff, int woff,
    const float* __restrict__ bKK, const float* __restrict__ wK1,
    const float* __restrict__ bK1p, float* __restrict__ hx) {
  int w = tid >> 6, lane = tid & 63, l15 = lane & 15, quad = lane >> 4;
  const half8* fH = (const half8*)fH16;
  {
    int nn = tid >> 4, i = tid & 15;
    idxLm[nn * 33 + i] = idxTab[(size_t)(n0 + nn) * istr + ioff + i];
  }
  __syncthreads();
  const half8* wHv = (const half8*)(wH16 + woff);
  f32x4 coef = {0.f, 0.f, 0.f, 0.f};
#pragma unroll
  for (int ii = 0; ii < 4; ii++) {
    int i = w * 4 + ii;
    int rowi = idxLm[l15 * 33 + i];
    float bkk = bKK[i * 16 + l15];
    f32x4 acc = {0.f, 0.f, 0.f, 0.f};
#pragma unroll
    for (int kc = 0; kc < 4; kc++) {
      half8 ah = fH[(size_t)rowi * 16 + kc * 4 + quad];
      half8 bh = wHv[((size_t)i * 16 + l15) * 16 + kc * 4 + quad];
      acc = __builtin_amdgcn_mfma_f32_16x16x32_f16(ah, bh, acc, 0, 0, 0);
    }
    float wki = wK1[i];
#pragma unroll
    for (int r = 0; r < 4; r++) {
      float v = acc[r] + bkk;
      float mx = v;
#pragma unroll
      for (int msk = 1; msk < 16; msk <<= 1) mx = fmaxf(mx, __shfl_xor(mx, msk));
      float e = __expf(v - mx);
      float s = e;
#pragma unroll
      for (int msk = 1; msk < 16; msk <<= 1) s += __shfl_xor(s, msk);
      coef[r] += wki * (e / s);
    }
  }
#pragma unroll
  for (int r = 0; r < 4; r++) coefPm[(w * 16 + quad * 4 + r) * 33 + l15] = coef[r];
  __syncthreads();
  {
    int nn = tid >> 4, j = tid & 15;
    coefSm[nn * 33 + j] = coefPm[(nn) * 33 + j] + coefPm[(16 + nn) * 33 + j] +
                          coefPm[(32 + nn) * 33 + j] + coefPm[(48 + nn) * 33 + j];
  }
  __syncthreads();
  {
    int nl = tid >> 4, g = tid & 15;
    float bk1 = bK1p[0];
    float a8[8];
#pragma unroll
    for (int t = 0; t < 8; t++) a8[t] = bk1;
    for (int j = 0; j < 16; j++) {
      float cf = coefSm[nl * 33 + j];
      int rowj = idxLm[nl * 33 + j];
      half8 xv = fH[(size_t)rowj * 16 + g];
#pragma unroll
      for (int e = 0; e < 8; e++) a8[e] = fmaf(cf, (float)xv[e], a8[e]);
    }
    int node = n0 + nl;
    float4* o = (float4*)(hx + ((size_t)node * T_HE + tslot) * D + g * 8);
    o[0] = make_float4(a8[0], a8[1], a8[2], a8[3]);
    o[1] = make_float4(a8[4], a8[5], a8[6], a8[7]);
  }
}

__device__ __forceinline__ void vc32_body(int tid, int n0,
    int* idxLm, float* coefPm, float* coefSm,
    const _Float16* __restrict__ fH16, const _Float16* __restrict__ wH16,
    const int* __restrict__ struct_idx,
    const float* __restrict__ bKK_s, const float* __restrict__ wK1_s,
    const float* __restrict__ bK1_s, float* __restrict__ hx) {
  int w = tid >> 6, lane = tid & 63, l15 = lane & 15, quad = lane >> 4;
  const half8* fH = (const half8*)fH16;
  for (int e = tid; e < 512; e += 256) {
    int nn = e >> 5, i = e & 31;
    idxLm[nn * 33 + i] = struct_idx[(size_t)(n0 + nn) * 32 + i];
  }
  __syncthreads();
  const half8* wHv = (const half8*)(wH16 + 65536);
  f32x4 coef0 = {0.f, 0.f, 0.f, 0.f};
  f32x4 coef1 = {0.f, 0.f, 0.f, 0.f};
#pragma unroll
  for (int ii = 0; ii < 8; ii++) {
    int i = w * 8 + ii;
    int rowi = idxLm[l15 * 33 + i];
    float bk0 = bKK_s[i * 32 + l15];
    float bk1v = bKK_s[i * 32 + 16 + l15];
    f32x4 a0 = {0.f, 0.f, 0.f, 0.f};
    f32x4 a1 = {0.f, 0.f, 0.f, 0.f};
#pragma unroll
    for (int kc = 0; kc < 4; kc++) {
      half8 ah = fH[(size_t)rowi * 16 + kc * 4 + quad];
      half8 b0 = wHv[((size_t)i * 32 + l15) * 16 + kc * 4 + quad];
      half8 b1 = wHv[((size_t)i * 32 + 16 + l15) * 16 + kc * 4 + quad];
      a0 = __builtin_amdgcn_mfma_f32_16x16x32_f16(ah, b0, a0, 0, 0, 0);
      a1 = __builtin_amdgcn_mfma_f32_16x16x32_f16(ah, b1, a1, 0, 0, 0);
    }
    float wki = wK1_s[i];
#pragma unroll
    for (int r = 0; r < 4; r++) {
      float v0 = a0[r] + bk0, v1 = a1[r] + bk1v;
      float mx = fmaxf(v0, v1);
#pragma unroll
      for (int msk = 1; msk < 16; msk <<= 1) mx = fmaxf(mx, __shfl_xor(mx, msk));
      float e0 = __expf(v0 - mx), e1 = __expf(v1 - mx);
      float s = e0 + e1;
#pragma unroll
      for (int msk = 1; msk < 16; msk <<= 1) s += __shfl_xor(s, msk);
      float inv = wki / s;
      coef0[r] += e0 * inv;
      coef1[r] += e1 * inv;
    }
  }
#pragma unroll
  for (int r = 0; r < 4; r++) {
    coefPm[(w * 16 + quad * 4 + r) * 33 + l15] = coef0[r];
    coefPm[(w * 16 + quad * 4 + r) * 33 + l15 + 16] = coef1[r];
  }
  __syncthreads();
  for (int e = tid; e < 512; e += 256) {
    int nn = e >> 5, j = e & 31;
    coefSm[nn * 33 + j] = coefPm[nn * 33 + j] + coefPm[(16 + nn) * 33 + j] +
                          coefPm[(32 + nn) * 33 + j] + coefPm[(48 + nn) * 33 + j];
  }
  __syncthreads();
  {
    int nl = tid >> 4, g = tid & 15;
    float bk1 = bK1_s[0];
    float a8[8];
#pragma unroll
    for (int t = 0; t < 8; t++) a8[t] = bk1;
    for (int j = 0; j < 32; j++) {
      float cf = coefSm[nl * 33 + j];
      int rowj = idxLm[nl * 33 + j];
      half8 xv = fH[(size_t)rowj * 16 + g];
#pragma unroll
      for (int e = 0; e < 8; e++) a8[e] = fmaf(cf, (float)xv[e], a8[e]);
    }
    int node = n0 + nl;
    float4* o = (float4*)(hx + ((size_t)node * T_HE + 4) * D + g * 8);
    o[0] = make_float4(a8[0], a8[1], a8[2], a8[3]);
    o[1] = make_float4(a8[4], a8[5], a8[6], a8[7]);
  }
}

// ---------------- MEGA: bf16 MFMA sim (in-register top-16) + vc branches 0,1,2,struct ----------------
// grid 3792, interleave: bx%3==0 -> sim block sid=bx/3 (1264: rb=sid%79,
// chunk=sid/79); else vc block vid=(bx/3)*2+(bx%3-1) (2500 used). Union LDS
// 16KB (sim: 64-col B tiles; vc: 12.7KB) -> 6 blocks/CU at launch_bounds(256,6).
__global__ __launch_bounds__(256, 6) void ksimvc(
    const unsigned short* __restrict__ xnh, unsigned* __restrict__ cand,
    const _Float16* __restrict__ fH16, const _Float16* __restrict__ wH16,
    const int* __restrict__ cluster_idx, const int* __restrict__ struct_idx,
    const float* __restrict__ bKK_c, const float* __restrict__ bKK_s,
    const float* __restrict__ wK1_c, const float* __restrict__ bK1_c,
    const float* __restrict__ wK1_s, const float* __restrict__ bK1_s,
    float* __restrict__ hx) {
  __shared__ __align__(16) unsigned char smem[16384];
  int bx = blockIdx.x;
  int tid = threadIdx.x;
  int r3 = bx % 3, q3 = bx / 3;
  if (r3 == 0) {
    // ---------------- sim (64-col tiles, 16KB LDS) ----------------
    short* Bb = (short*)smem;             // [kp<16][ci<64][8 bf16] = 16 KB
    int rb = q3 % 79, chunk = q3 / 79;
    int w = tid >> 6, lane = tid & 63, l31 = lane & 31, lh = lane >> 5;
    int row0 = rb * 128 + w * 32;
    int cbase = chunk * CHUNK;

    short8 afr[8];   // B operand: n = l31 (our row), k = ks*16 + lh*8
    {
      int ar = min(row0 + l31, N_NODES - 1);
      const short8* ap = (const short8*)(xnh + (size_t)ar * D);
#pragma unroll
      for (int ks = 0; ks < 8; ks++) afr[ks] = ap[ks * 2 + lh];
    }

    unsigned run[16];
#pragma unroll
    for (int s = 0; s < 16; s++) run[s] = 0u;

    for (int ti = 0; ti < 10; ti++) {
      int tb = cbase + ti * 64;
      __syncthreads();
      {  // stage 64 cols k-major; 4 threads per col, fully coalesced 256B rows
        int ci = tid >> 2, part = tid & 3;
        int gcol = min(tb + ci, N_NODES - 1);
        const short8* gp = (const short8*)(xnh + (size_t)gcol * D);
        short8* bp = (short8*)Bb;
#pragma unroll
        for (int i = 0; i < 4; i++) bp[(part * 4 + i) * 64 + ci] = gp[part * 4 + i];
      }
      __syncthreads();

      const short8* bv = (const short8*)Bb;
      f32x16 acc[2];
#pragma unroll
      for (int nj = 0; nj < 2; nj++)
#pragma unroll
        for (int r = 0; r < 16; r++) acc[nj][r] = 0.f;
#pragma unroll
      for (int ks = 0; ks < 8; ks++) {
        int kp = ks * 2 + lh;
#pragma unroll
        for (int nj = 0; nj < 2; nj++) {
          short8 af = bv[kp * 64 + nj * 32 + l31];   // A: m = l31 (cand col)
          acc[nj] = __builtin_amdgcn_mfma_f32_32x32x16_bf16(af, afr[ks], acc[nj], 0, 0, 0);
        }
      }
#pragma unroll
      for (int nj = 0; nj < 2; nj++) {
        unsigned bt[16];
#pragma unroll
        for (int reg = 0; reg < 16; reg++) {
          int m = (reg & 3) + 8 * (reg >> 2) + 4 * lh;
          int cic = ti * 64 + nj * 32 + m;
          unsigned bb = __float_as_uint(acc[nj][reg]);
          unsigned mu = (bb & 0x80000000u) ? ~bb : (bb | 0x80000000u);
          bt[reg] = (cic < CHUNK) ? ((mu & 0xFFFFFC00u) | (unsigned)(1023 - cic)) : 0u;
        }
        sort16_asc(bt);
        merge16_asc(run, bt);
      }
    }
    {
      unsigned other[16];
#pragma unroll
      for (int s = 0; s < 16; s++) other[s] = (unsigned)__shfl_xor((int)run[s], 32);
      merge16_asc(run, other);
    }
    int grow = row0 + l31;
    if (lh == 0 && grow < N_NODES) {
      unsigned* o = cand + ((size_t)grow * NCH + chunk) * 16;
#pragma unroll
      for (int i = 0; i < 16; i += 4)
        *(uint4*)(o + i) = make_uint4(run[i], run[i + 1], run[i + 2], run[i + 3]);
    }
  } else {
    // ---------------- vertex conv (knn-independent branches) ----------------
    int vid = q3 * 2 + (r3 - 1);
    if (vid >= 2500) return;
    int zz = vid / 625, bi = vid - zz * 625;
    int n0 = bi * 16;
    int* idxLm = (int*)smem;
    float* coefPm = (float*)(smem + 2112);
    float* coefSm = (float*)(smem + 10560);
    if (zz < 3) {
      vc16_body(tid, n0, zz, idxLm, coefPm, coefSm, fH16, wH16,
                cluster_idx, NCB * 16, zz * 16, 0, bKK_c, wK1_c, bK1_c, hx);
    } else {
      vc32_body(tid, n0, idxLm, coefPm, coefSm, fH16, wH16,
                struct_idx, bKK_s, wK1_s, bK1_s, hx);
    }
  }
}

// ---------------- knn vertex conv (after krerank) ----------------
__global__ __launch_bounds__(256, 6) void kvc3(
    const _Float16* __restrict__ fH16, const _Float16* __restrict__ wH16,
    const int* __restrict__ knn,
    const float* __restrict__ bKK_n, const float* __restrict__ wK1_n,
    const float* __restrict__ bK1_n, float* __restrict__ hx) {
  __shared__ __align__(16) unsigned char smem[12672];
  int* idxLm = (int*)smem;
  float* coefPm = (float*)(smem + 2112);
  float* coefSm = (float*)(smem + 10560);
  vc16_body(threadIdx.x, blockIdx.x * 16, 3, idxLm, coefPm, coefSm, fH16, wH16,
            knn, 16, 0, 32768, bKK_n, wK1_n, bK1_n, hx);
}

// ---------------- merge chunk keys -> top-32 candidate cols ----------------
__global__ __launch_bounds__(64) void kmerge(const unsigned* __restrict__ cand,
                                             int* __restrict__ candIdx) {
  int row = blockIdx.x * 64 + threadIdx.x;
  if (row >= N_NODES) return;
  unsigned long long run[TOPM];
#pragma unroll
  for (int s = 0; s < TOPM; s++) run[s] = 0ull;
  const uint4* c4 = (const uint4*)(cand + (size_t)row * (NCH * 16));
  for (int ch = 0; ch < NCH; ch++) {
    unsigned b[16];
#pragma unroll
    for (int q = 0; q < 4; q++) {
      uint4 t = c4[ch * 4 + q];
      b[q * 4 + 0] = t.x; b[q * 4 + 1] = t.y;
      b[q * 4 + 2] = t.z; b[q * 4 + 3] = t.w;
    }
    unsigned base = (unsigned)(ch * CHUNK);
    unsigned long long b64[16];
#pragma unroll
    for (int s = 0; s < 16; s++) {
      unsigned k = b[s];
      unsigned gcol = base + (1023u - (k & 1023u));
      b64[s] = ((unsigned long long)(k >> 10) << 32) | (unsigned long long)(~gcol);
    }
#pragma unroll
    for (int i = 0; i < 16; i++) run[i] = max(run[i], b64[15 - i]);
#pragma unroll
    for (int j = 16; j > 0; j >>= 1)
#pragma unroll
      for (int i = 0; i < TOPM; i++)
        if ((i & j) == 0) ceu64(run[i], run[i + j]);
  }
  int4* o4 = (int4*)(candIdx + (size_t)row * TOPM);
#pragma unroll
  for (int s = 0; s < TOPM; s += 4) {
    int4 o;
    o.x = (int)(~(unsigned)(run[s + 0] & 0xFFFFFFFFull));
    o.y = (int)(~(unsigned)(run[s + 1] & 0xFFFFFFFFull));
    o.z = (int)(~(unsigned)(run[s + 2] & 0xFFFFFFFFull));
    o.w = (int)(~(unsigned)(run[s + 3] & 0xFFFFFFFFull));
    o4[s >> 2] = o;
  }
}

// ---------------- f64 exact re-rank of 32 candidates -> knn top-16 ----------------
__global__ __launch_bounds__(256) void krerank(const float* __restrict__ feats,
                                               const double* __restrict__ normD,
                                               const int* __restrict__ candIdx,
                                               int* __restrict__ knn) {
  __shared__ float rowF[D];
  __shared__ double simL[TOPM];
  __shared__ int idxL[TOPM];
  int row = blockIdx.x;
  int tid = threadIdx.x;
  if (tid < DQ)
    ((float4*)rowF)[tid] = ((const float4*)(feats + (size_t)row * D))[tid];
  int c = tid >> 3, part = tid & 7;
  int cnd = candIdx[(size_t)row * TOPM + c];
  __syncthreads();
  const float4* f4 = (const float4*)(feats + (size_t)cnd * D);
  double acc = 0.0;
#pragma unroll
  for (int g = 0; g < 4; g++) {
    float4 v = f4[part * 4 + g];
    const float* rf = &rowF[(part * 4 + g) * 4];
    acc = fma((double)v.x, (double)rf[0], acc);
    acc = fma((double)v.y, (double)rf[1], acc);
    acc = fma((double)v.z, (double)rf[2], acc);
    acc = fma((double)v.w, (double)rf[3], acc);
  }
  acc += __shfl_down(acc, 4);
  acc += __shfl_down(acc, 2);
  acc += __shfl_down(acc, 1);
  if (part == 0) {
    simL[c] = acc / (normD[row] * normD[cnd]);
    idxL[c] = cnd;
  }
  __syncthreads();
  if (tid < TOPM) {
    double s = simL[tid];
    int idx = idxL[tid];
    int rank = 0;
#pragma unroll
    for (int o = 0; o < TOPM; o++) {
      double so = simL[o];
      int io = idxL[o];
      rank += (so > s || (so == s && io < idx)) ? 1 : 0;
    }
    if (rank < TOPK) knn[(size_t)row * TOPK + rank] = idx;
  }
}

// ---------------- edge attention + fc (float4 LDS) ----------------
__global__ __launch_bounds__(256) void kfinal(const float* __restrict__ hx,
    const float* __restrict__ w1, const float* __restrict__ b1,
    const float* __restrict__ w2, const float* __restrict__ b2p,
    const float* __restrict__ fcw, const float* __restrict__ fcb,
    float* __restrict__ out) {
  __shared__ float xL[8][T_HE][D];
  __shared__ float hL[8][T_HE][HID_SZ];
  __shared__ float scL[8][T_HE];
  __shared__ float aggL[8][D];
  int tid = threadIdx.x;
  int n0 = blockIdx.x * 8;
  const float4* hx4 = (const float4*)hx;
  for (int q = tid; q < 8 * T_HE * DQ; q += 256) {
    int nn = q / (T_HE * DQ);
    int rem = q - nn * (T_HE * DQ);
    int t = rem / DQ;
    int dq = rem & 31;
    int node = n0 + nn;
    float4 val = make_float4(0.f, 0.f, 0.f, 0.f);
    if (node < N_NODES) val = hx4[((size_t)node * T_HE + t) * DQ + dq];
    *(float4*)&xL[nn][t][dq << 2] = val;
  }
  __syncthreads();
  for (int q = tid; q < 8 * T_HE * HID_SZ; q += 256) {
    int nn = q / (T_HE * HID_SZ);
    int rem = q - nn * (T_HE * HID_SZ);
    int t = rem / HID_SZ;
    int hh = rem & (HID_SZ - 1);
    float acc = b1[hh];
    const float4* xv4 = (const float4*)xL[nn][t];
    for (int dq = 0; dq < 32; dq++) {
      float4 xv = xv4[dq];
      int db = dq * 4;
      acc = fmaf(xv.x, w1[(db + 0) * HID_SZ + hh], acc);
      acc = fmaf(xv.y, w1[(db + 1) * HID_SZ + hh], acc);
      acc = fmaf(xv.z, w1[(db + 2) * HID_SZ + hh], acc);
      acc = fmaf(xv.w, w1[(db + 3) * HID_SZ + hh], acc);
    }
    hL[nn][t][hh] = fmaxf(acc, 0.f);
  }
  __syncthreads();
  if (tid < 8 * T_HE) {
    int nn = tid / T_HE, t = tid % T_HE;
    float acc = b2p[0];
    for (int hh = 0; hh < HID_SZ; hh++) acc = fmaf(hL[nn][t][hh], w2[hh], acc);
    scL[nn][t] = acc;
  }
  __syncthreads();
  if (tid < 8) {
    float mx = -1e30f;
#pragma unroll
    for (int t = 0; t < T_HE; t++) mx = fmaxf(mx, scL[tid][t]);
    float e[T_HE];
    float s = 0.f;
#pragma unroll
    for (int t = 0; t < T_HE; t++) { e[t] = expf(scL[tid][t] - mx); s += e[t]; }
    float inv = 1.f / s;
#pragma unroll
    for (int t = 0; t < T_HE; t++) scL[tid][t] = e[t] * inv;
  }
  __syncthreads();
  {
    int nn = tid >> 5, dq = tid & 31;
    float4 acc = make_float4(0.f, 0.f, 0.f, 0.f);
#pragma unroll
    for (int t = 0; t < T_HE; t++) {
      float sw = scL[nn][t];
      float4 xv = *(const float4*)&xL[nn][t][dq << 2];
      acc.x = fmaf(sw, xv.x, acc.x);
      acc.y = fmaf(sw, xv.y, acc.y);
      acc.z = fmaf(sw, xv.z, acc.z);
      acc.w = fmaf(sw, xv.w, acc.w);
    }
    *(float4*)&aggL[nn][dq << 2] = acc;
  }
  __syncthreads();
  {
    int dout = tid & 127, g = tid >> 7;
    float a0 = fcb[dout], a1 = a0, a2 = a0, a3 = a0;
    for (int dq = 0; dq < 32; dq++) {
      int db = dq * 4;
      float wv0 = fcw[(db + 0) * 128 + dout];
      float wv1 = fcw[(db + 1) * 128 + dout];
      float wv2 = fcw[(db + 2) * 128 + dout];
      float wv3 = fcw[(db + 3) * 128 + dout];
      float4 v0 = *(const float4*)&aggL[g * 4 + 0][db];
      float4 v1 = *(const float4*)&aggL[g * 4 + 1][db];
      float4 v2 = *(const float4*)&aggL[g * 4 + 2][db];
      float4 v3 = *(const float4*)&aggL[g * 4 + 3][db];
      a0 = fmaf(v0.x, wv0, fmaf(v0.y, wv1, fmaf(v0.z, wv2, fmaf(v0.w, wv3, a0))));
      a1 = fmaf(v1.x, wv0, fmaf(v1.y, wv1, fmaf(v1.z, wv2, fmaf(v1.w, wv3, a1))));
      a2 = fmaf(v2.x, wv0, fmaf(v2.y, wv1, fmaf(v2.z, wv2, fmaf(v2.w, wv3, a2))));
      a3 = fmaf(v3.x, wv0, fmaf(v3.y, wv1, fmaf(v3.z, wv2, fmaf(v3.w, wv3, a3))));
    }
    int nb = n0 + g * 4;
    if (nb + 0 < N_NODES) out[(size_t)(nb + 0) * 128 + dout] = fmaxf(a0, 0.f);
    if (nb + 1 < N_NODES) out[(size_t)(nb + 1) * 128 + dout] = fmaxf(a1, 0.f);
    if (nb + 2 < N_NODES) out[(size_t)(nb + 2) * 128 + dout] = fmaxf(a2, 0.f);
    if (nb + 3 < N_NODES) out[(size_t)(nb + 3) * 128 + dout] = fmaxf(a3, 0.f);
  }
}

extern "C" void kernel_launch(void* const* d_in, const int* in_sizes, int n_in,
                              void* d_out, int out_size, void* d_ws, size_t ws_size,
                              hipStream_t stream) {
  (void)in_sizes; (void)n_in; (void)out_size; (void)ws_size;
  const float* feats       = (const float*)d_in[1];
  const int*   cluster_idx = (const int*)d_in[2];
  const int*   struct_idx  = (const int*)d_in[3];
  const float* wKK_c = (const float*)d_in[5];
  const float* bKK_c = (const float*)d_in[6];
  const float* wK1_c = (const float*)d_in[7];
  const float* bK1_c = (const float*)d_in[8];
  const float* wKK_n = (const float*)d_in[9];
  const float* bKK_n = (const float*)d_in[10];
  const float* wK1_n = (const float*)d_in[11];
  const float* bK1_n = (const float*)d_in[12];
  const float* wKK_s = (const float*)d_in[13];
  const float* bKK_s = (const float*)d_in[14];
  const float* wK1_s = (const float*)d_in[15];
  const float* bK1_s = (const float*)d_in[16];
  const float* ec_w1 = (const float*)d_in[17];
  const float* ec_b1 = (const float*)d_in[18];
  const float* ec_w2 = (const float*)d_in[19];
  const float* ec_b2 = (const float*)d_in[20];
  const float* fc_w  = (const float*)d_in[21];
  const float* fc_b  = (const float*)d_in[22];
  float* out = (float*)d_out;

  // ws layout (lifetime-overlapped, <= 72.32 MB):
  //  [0, 2.56M)         xnh (bf16)
  //  [2.56M, 12.8M)     cand (u32)
  //  [12.8M, 14.08M)    candIdx (int)
  //  [14.08M, 14.16M)   normD (f64)
  //  [14.16M, 16.72M)   fH16 (fp16 feats, 2.56 MB)
  //  [16.72M, 17.12M)   wH16 (fp16 W: c|n|s = 32768|32768|131072 halves)
  //  [46.08M, 46.72M)   knn (int)
  //  [46.72M, 72.32M)   hx (f32)
  char* wsb = (char*)d_ws;
  unsigned short* xnh = (unsigned short*)(wsb);
  unsigned* cand = (unsigned*)(wsb + 2560000);
  int* candIdx = (int*)(wsb + 12800000);
  double* normD = (double*)(wsb + 14080000);
  _Float16* fH16 = (_Float16*)(wsb + 14160000);
  _Float16* wH16 = (_Float16*)(wsb + 16720000);
  int* knnIdx = (int*)(wsb + 46080000);
  float* hx = (float*)(wsb + 46720000);

  kpre<<<2884, 256, 0, stream>>>(feats, wKK_c, wKK_n, wKK_s,
                                 xnh, fH16, normD, wH16);
  ksimvc<<<3792, 256, 0, stream>>>(xnh, cand, fH16, wH16, cluster_idx, struct_idx,
                                   bKK_c, bKK_s, wK1_c, bK1_c, wK1_s, bK1_s, hx);
  kmerge<<<(N_NODES + 63) / 64, 64, 0, stream>>>(cand, candIdx);
  krerank<<<N_NODES, 256, 0, stream>>>(feats, normD, candIdx, knnIdx);
  kvc3<<<625, 256, 0, stream>>>(fH16, wH16, knnIdx, bKK_n, wK1_n, bK1_n, hx);
  kfinal<<<1250, 256, 0, stream>>>(hx, ec_w1, ec_b1, ec_w2, ec_b2, fc_w, fc_b, out);
}